// Round 8
// baseline (83.458 us; speedup 1.0000x reference)
//
#include <hip/hip_runtime.h>

// VQ-VAE vector quantizer, MI355X — v6: fused score+scatter.
// Block = 32 tokens x ALL 512 codes (4 waves x 128 codes), grid 2048.
// x-tile staged via global_load_lds (pre-swizzled global -> linear LDS);
// codes' A-frags streamed from L2-hot e-split; output written directly.
// score(t,k) = x_t . e_k - 0.5*||e_k||^2  (argmax == argmin distance)
// x.e = xh.eh + (xh.el' + xl'.eh)/2048, *_lo' = (v - fp16(v))*2048 as fp16.

typedef _Float16 f16;
typedef _Float16 f16x4 __attribute__((ext_vector_type(4)));
typedef _Float16 f16x8 __attribute__((ext_vector_type(8)));
typedef float f32x16 __attribute__((ext_vector_type(16)));

#define ND 128
#define NK 512
#define NHW 4096
#define NTOK 65536
#define LO_SCALE 2048.0f
#define LO_INV (1.0f / 2048.0f)

// workspace layout (bytes)
#define WS_XHI 0
#define WS_XLO 16777216u
#define WS_EHI 33554432u
#define WS_ELO 33685504u
#define WS_ENS 33816576u
#define WS_NEED 33818624u

__device__ __forceinline__ unsigned mono_key(float v) {
  const unsigned u = __float_as_uint(v);
  return (u & 0x80000000u) ? ~u : (u | 0x80000000u);
}

// ================================================================ prep ======
// blocks 0..1023: transpose+split x (SWIZZLED slots in global)
// blocks 1024..1055: split e PLAIN + 0.5*||e||^2
__global__ __launch_bounds__(256) void vq_prep3(const float* __restrict__ x,
                                                const float* __restrict__ e,
                                                f16* __restrict__ xhi, f16* __restrict__ xlo,
                                                f16* __restrict__ ehi, f16* __restrict__ elo,
                                                float* __restrict__ ens) {
  const int tid = threadIdx.x;
  if (blockIdx.x < 1024) {
    __shared__ float sc[ND][65];
    const int tok0 = blockIdx.x * 64;
    const int b = blockIdx.x >> 6;
    const int hw0 = (blockIdx.x & 63) * 64;
    const float* xb = x + (size_t)b * ND * NHW + hw0;
    #pragma unroll
    for (int it = 0; it < 8; ++it) {
      const int f = tid + 256 * it;
      const int d = f >> 4, t4 = (f & 15) * 4;
      const float4 v = *(const float4*)(xb + (size_t)d * NHW + t4);
      sc[d][t4 + 0] = v.x; sc[d][t4 + 1] = v.y;
      sc[d][t4 + 2] = v.z; sc[d][t4 + 3] = v.w;
    }
    __syncthreads();
    const int oct = tid & 15, trow = tid >> 4;
    #pragma unroll
    for (int p = 0; p < 4; ++p) {
      const int t = p * 16 + trow;
      const int tok = tok0 + t;
      float v[8];
      #pragma unroll
      for (int j = 0; j < 8; ++j) v[j] = sc[oct * 8 + j][t];
      f16x8 h, l;
      #pragma unroll
      for (int j = 0; j < 8; ++j) {
        const f16 hv = (f16)v[j];
        h[j] = hv;
        l[j] = (f16)((v[j] - (float)hv) * LO_SCALE);
      }
      const size_t off = (size_t)tok * ND + (size_t)((oct ^ (tok & 15)) * 8);
      *(f16x8*)(xhi + off) = h;
      *(f16x8*)(xlo + off) = l;
    }
  } else {
    const int k0 = ((int)blockIdx.x - 1024) * 16;
    const int r = tid >> 4, dq16 = tid & 15;
    const int k = k0 + r;
    float ssum = 0.0f;
    #pragma unroll
    for (int hh = 0; hh < 2; ++hh) {
      const int dq = dq16 + 16 * hh;
      const float4 v = *(const float4*)(e + (size_t)k * ND + 4 * dq);
      ssum += v.x * v.x + v.y * v.y + v.z * v.z + v.w * v.w;
      float va[4] = {v.x, v.y, v.z, v.w};
      f16x4 hv, lv;
      #pragma unroll
      for (int j = 0; j < 4; ++j) {
        const f16 h = (f16)va[j];
        hv[j] = h;
        lv[j] = (f16)((va[j] - (float)h) * LO_SCALE);
      }
      const size_t off = (size_t)k * ND + 4 * dq;   // PLAIN layout
      *(f16x4*)(ehi + off) = hv;
      *(f16x4*)(elo + off) = lv;
    }
    #pragma unroll
    for (int m = 1; m < 16; m <<= 1) ssum += __shfl_xor(ssum, m, 64);
    if (dq16 == 0) ens[k] = 0.5f * ssum;
  }
}

// ========================================================= fused score ======
// grid 2048 blocks x 256 thr (4 waves). Block = tokens T0..T0+31, all codes.
// Wave w: codes w*128..+128 in 4 cgroups of 32. acc 2x16, Ah/Al 64 regs.
__global__ __launch_bounds__(256) void vq_score(const f16* __restrict__ xhi,
                                                const f16* __restrict__ xlo,
                                                const f16* __restrict__ ehi,
                                                const f16* __restrict__ elo,
                                                const float* __restrict__ ens,
                                                const float* __restrict__ e32,
                                                float* __restrict__ out) {
  __shared__ f16 xsh[32 * 128];                // 8KB (swizzled slots)
  __shared__ f16 xsl[32 * 128];                // 8KB
  __shared__ float ens_s[NK];                  // 2KB
  __shared__ unsigned long long cand[32][5];   // 1.3KB (+pad col)
  __shared__ int bidx_s[32];

  const int tid = threadIdx.x;                 // 0..255
  const int w = tid >> 6;                      // wave 0..3
  const int lane = tid & 63;
  const int l31 = lane & 31;
  const int half = lane >> 5;
  const int T0 = (int)blockIdx.x * 32;

  // stage x tile: pre-swizzled global -> linear LDS, no VGPR round-trip
  {
    const f16* sh = xhi + (size_t)T0 * ND;
    const f16* sl = xlo + (size_t)T0 * ND;
    __builtin_amdgcn_global_load_lds(sh + tid * 8,        &xsh[tid * 8],        16, 0, 0);
    __builtin_amdgcn_global_load_lds(sh + 2048 + tid * 8, &xsh[2048 + tid * 8], 16, 0, 0);
    __builtin_amdgcn_global_load_lds(sl + tid * 8,        &xsl[tid * 8],        16, 0, 0);
    __builtin_amdgcn_global_load_lds(sl + 2048 + tid * 8, &xsl[2048 + tid * 8], 16, 0, 0);
  }
  ens_s[tid] = ens[tid];
  ens_s[tid + 256] = ens[tid + 256];
  __syncthreads();

  unsigned long long best = 0ull;
  #pragma unroll
  for (int cg = 0; cg < 4; ++cg) {
    // A fragments: this lane's code row (e hi/lo, plain layout, L2-hot)
    const int acode = w * 128 + cg * 32 + l31;
    f16x8 Ah[8], Al[8];
    #pragma unroll
    for (int ks = 0; ks < 8; ++ks) {
      const size_t off = (size_t)acode * ND + ks * 16 + half * 8;
      Ah[ks] = *(const f16x8*)(ehi + off);
      Al[ks] = *(const f16x8*)(elo + off);
    }

    f32x16 a1 = {}, a2 = {};
    __builtin_amdgcn_s_setprio(1);
    #pragma unroll
    for (int ks = 0; ks < 8; ++ks) {
      const int sl = ((2 * ks + half) ^ (l31 & 15)) * 8;
      const f16x8 bh = *(const f16x8*)&xsh[l31 * 128 + sl];
      const f16x8 bl = *(const f16x8*)&xsl[l31 * 128 + sl];
      a2 = __builtin_amdgcn_mfma_f32_32x32x16_f16(Al[ks], bh, a2, 0, 0, 0);
      a1 = __builtin_amdgcn_mfma_f32_32x32x16_f16(Ah[ks], bh, a1, 0, 0, 0);
      a2 = __builtin_amdgcn_mfma_f32_32x32x16_f16(Ah[ks], bl, a2, 0, 0, 0);
    }
    __builtin_amdgcn_s_setprio(0);

    // lane-local argmax over the 16 code rows (rowr ascends with r)
    float bv = -3.0e38f; int bi = 0;
    #pragma unroll
    for (int r = 0; r < 16; ++r) {
      const int rowr = (r & 3) + 8 * (r >> 2) + 4 * half;
      const int code = w * 128 + cg * 32 + rowr;
      const float s = a1[r] + a2[r] * LO_INV - ens_s[code];
      if (s > bv) { bv = s; bi = code; }
    }
    // merge across halves (same token for lane ^ 32)
    const float ov = __shfl_xor(bv, 32, 64);
    const int oi = __shfl_xor(bi, 32, 64);
    if (ov > bv || (ov == bv && oi < bi)) { bv = ov; bi = oi; }
    const unsigned long long key =
        ((unsigned long long)mono_key(bv) << 32) | (unsigned)(511 - bi);
    best = (key > best) ? key : best;   // u64 key fully orders; ties -> lower idx
  }

  if (half == 0) cand[l31][w] = best;
  __syncthreads();
  if (tid < 32) {
    unsigned long long k = cand[tid][0];
    #pragma unroll
    for (int j = 1; j < 4; ++j) {
      const unsigned long long kj = cand[tid][j];
      k = (kj > k) ? kj : k;
    }
    bidx_s[tid] = 511 - (int)(k & 0x1FFull);
  }
  __syncthreads();

  // gather winning e rows, scatter to NCHW (128B-contiguous along hw)
  const int tloc = tid & 31, dg = tid >> 5;            // 8 d-groups of 16
  const int bb = T0 >> 12;                             // tile never crosses b
  const int hw = (T0 & 4095) + tloc;
  const float* er = e32 + (size_t)bidx_s[tloc] * ND + dg * 16;
  float* ob = out + (size_t)bb * ND * NHW + (size_t)(dg * 16) * NHW + hw;
  #pragma unroll
  for (int j4 = 0; j4 < 4; ++j4) {
    const float4 ev = *(const float4*)(er + j4 * 4);
    ob[(size_t)(j4 * 4 + 0) * NHW] = ev.x;
    ob[(size_t)(j4 * 4 + 1) * NHW] = ev.y;
    ob[(size_t)(j4 * 4 + 2) * NHW] = ev.z;
    ob[(size_t)(j4 * 4 + 3) * NHW] = ev.w;
  }
}

// ======================================================== fp32 fallback =====
__global__ __launch_bounds__(128) void vq_enorm(const float* __restrict__ e,
                                                float* __restrict__ ensw) {
  const int k = blockIdx.x;
  const int d = threadIdx.x;
  const float v = e[k * ND + d];
  float s = v * v;
  #pragma unroll
  for (int off = 32; off > 0; off >>= 1) s += __shfl_down(s, off, 64);
  __shared__ float tmp[2];
  if ((d & 63) == 0) tmp[d >> 6] = s;
  __syncthreads();
  if (d == 0) ensw[k] = tmp[0] + tmp[1];
}

__global__ __launch_bounds__(256, 2) void vq_main_f32(const float* __restrict__ x,
                                                      const float* __restrict__ e,
                                                      const float* __restrict__ ensw,
                                                      float* __restrict__ out) {
  __shared__ float xs[ND][64];
  __shared__ float esh[ND][64];
  __shared__ float enh[NK];
  __shared__ float red_v[64][17];
  __shared__ int red_i[64][17];
  __shared__ int bidx[64];
  const int tid = threadIdx.x;
  const int b = blockIdx.x >> 6;
  const int hw0 = (blockIdx.x & 63) * 64;
  const float* xb = x + ((size_t)b * ND) * NHW;
  #pragma unroll
  for (int i = 0; i < 8; ++i) {
    const int f = tid + 256 * i;
    const int d = f >> 4, t4 = f & 15;
    const float4 v = *(const float4*)(xb + (size_t)d * NHW + hw0 + 4 * t4);
    *(float4*)&xs[d][4 * t4] = v;
  }
  #pragma unroll
  for (int i = 0; i < 2; ++i) enh[tid + 256 * i] = ensw[tid + 256 * i];
  const int t4 = tid & 15, m = tid >> 4;
  float bvv[4] = {-3.0e38f, -3.0e38f, -3.0e38f, -3.0e38f};
  int bii[4] = {0, 0, 0, 0};
  for (int kc = 0; kc < NK / 64; ++kc) {
    __syncthreads();
    #pragma unroll
    for (int i = 0; i < 8; ++i) {
      const int f = tid + 256 * i;
      const int kk = f & 63, dq = f >> 6;
      const float4 v = *(const float4*)(e + (size_t)(kc * 64 + kk) * ND + 4 * dq);
      esh[4 * dq + 0][kk] = v.x; esh[4 * dq + 1][kk] = v.y;
      esh[4 * dq + 2][kk] = v.z; esh[4 * dq + 3][kk] = v.w;
    }
    __syncthreads();
    float acc[4][4];
    #pragma unroll
    for (int a = 0; a < 4; ++a)
      #pragma unroll
      for (int cc = 0; cc < 4; ++cc) acc[a][cc] = 0.0f;
    #pragma unroll 8
    for (int d = 0; d < ND; ++d) {
      const float4 xv = *(const float4*)&xs[d][4 * t4];
      const float4 ev = *(const float4*)&esh[d][4 * m];
      const float xa[4] = {xv.x, xv.y, xv.z, xv.w};
      const float ea[4] = {ev.x, ev.y, ev.z, ev.w};
      #pragma unroll
      for (int a = 0; a < 4; ++a)
        #pragma unroll
        for (int cc = 0; cc < 4; ++cc) acc[a][cc] = fmaf(xa[a], ea[cc], acc[a][cc]);
    }
    const int kbase = kc * 64 + 4 * m;
    #pragma unroll
    for (int cc = 0; cc < 4; ++cc) {
      const float bias = 0.5f * enh[kbase + cc];
      const int kg = kbase + cc;
      #pragma unroll
      for (int a = 0; a < 4; ++a) {
        const float s = acc[a][cc] - bias;
        if (s > bvv[a] || (s == bvv[a] && kg < bii[a])) { bvv[a] = s; bii[a] = kg; }
      }
    }
  }
  #pragma unroll
  for (int a = 0; a < 4; ++a) { red_v[4 * t4 + a][m] = bvv[a]; red_i[4 * t4 + a][m] = bii[a]; }
  __syncthreads();
  if (tid < 64) {
    float v = red_v[tid][0]; int ix = red_i[tid][0];
    #pragma unroll
    for (int j = 1; j < 16; ++j) {
      const float vj = red_v[tid][j]; const int ij = red_i[tid][j];
      if (vj > v || (vj == v && ij < ix)) { v = vj; ix = ij; }
    }
    bidx[tid] = ix;
  }
  __syncthreads();
  const int t = tid & 63, dgg = tid >> 6;
  const float* er = e + (size_t)bidx[t] * ND;
  float* ob = out + ((size_t)b * ND) * NHW + hw0 + t;
  #pragma unroll
  for (int i = 0; i < 32; ++i) ob[(size_t)(dgg * 32 + i) * NHW] = er[dgg * 32 + i];
}

// --------------------------------------------------------------- launch -----
extern "C" void kernel_launch(void* const* d_in, const int* in_sizes, int n_in,
                              void* d_out, int out_size, void* d_ws, size_t ws_size,
                              hipStream_t stream) {
  const float* x = (const float*)d_in[0];
  const float* e = (const float*)d_in[1];
  float* out = (float*)d_out;
  char* ws = (char*)d_ws;

  if (ws_size >= WS_NEED) {
    f16* xhi = (f16*)(ws + WS_XHI);
    f16* xlo = (f16*)(ws + WS_XLO);
    f16* ehi = (f16*)(ws + WS_EHI);
    f16* elo = (f16*)(ws + WS_ELO);
    float* ens = (float*)(ws + WS_ENS);
    vq_prep3<<<1056, 256, 0, stream>>>(x, e, xhi, xlo, ehi, elo, ens);
    vq_score<<<2048, 256, 0, stream>>>(xhi, xlo, ehi, elo, ens, e, out);
  } else {
    float* ensw = (float*)d_ws;
    vq_enorm<<<NK, 128, 0, stream>>>(e, ensw);
    vq_main_f32<<<16 * 64, 256, 0, stream>>>(x, e, ensw, out);
  }
}

// Round 9
// 52.510 us; speedup vs baseline: 1.5894x; 1.5894x over previous
//
#include <hip/hip_runtime.h>

// VQ-VAE vector quantizer, MI355X — v7: x-resident-in-registers score kernel.
// Block: 256 thr / 4 waves / 128 tokens; wave owns 32 tokens (B-frags, 64 VGPR,
// loaded once from fragment-ordered global). Codes stream through double-buffered
// LDS (8 chunks x 64 codes) via global_load_lds (zero staging VGPRs).
// Lane-local argmax (col=token) + half-merge + fused direct output write.
// score(t,k) = x_t . e_k - 0.5*||e_k||^2  (argmax == argmin distance)
// x.e = xh.eh + (xh.el' + xl'.eh)/2048, *_lo' = (v - fp16(v))*2048 as fp16.

typedef _Float16 f16;
typedef _Float16 f16x4 __attribute__((ext_vector_type(4)));
typedef _Float16 f16x8 __attribute__((ext_vector_type(8)));
typedef float f32x16 __attribute__((ext_vector_type(16)));

#define ND 128
#define NK 512
#define NHW 4096
#define LO_SCALE 2048.0f
#define LO_INV (1.0f / 2048.0f)

// workspace layout (bytes)
#define WS_XHI 0
#define WS_XLO 16777216u
#define WS_EHI 33554432u
#define WS_ELO 33685504u
#define WS_ENS 33816576u
#define WS_NEED 33818624u

// ================================================================ prep ======
// blocks 0..1023: transpose+split x into FRAGMENT-MAJOR layout:
//   xhi[(tok>>5)*4096 + kslot*256 + (tok&31)*8 .. +8], kslot = d-octet 0..15
// blocks 1024..1055: split e SWIZZLED (16B slot ^= code&15) + 0.5*||e||^2
__global__ __launch_bounds__(256) void vq_prep(const float* __restrict__ x,
                                               const float* __restrict__ e,
                                               f16* __restrict__ xhi, f16* __restrict__ xlo,
                                               f16* __restrict__ ehi, f16* __restrict__ elo,
                                               float* __restrict__ ens) {
  const int tid = threadIdx.x;
  if (blockIdx.x < 1024) {
    __shared__ float sc[ND][65];
    const int tok0 = blockIdx.x * 64;
    const int b = blockIdx.x >> 6;
    const int hw0 = (blockIdx.x & 63) * 64;
    const float* xb = x + (size_t)b * ND * NHW + hw0;
    #pragma unroll
    for (int it = 0; it < 8; ++it) {
      const int f = tid + 256 * it;
      const int d = f >> 4, t4 = (f & 15) * 4;
      const float4 v = *(const float4*)(xb + (size_t)d * NHW + t4);
      sc[d][t4 + 0] = v.x; sc[d][t4 + 1] = v.y;
      sc[d][t4 + 2] = v.z; sc[d][t4 + 3] = v.w;
    }
    __syncthreads();
    const int oct = tid & 15, trow = tid >> 4;
    #pragma unroll
    for (int p = 0; p < 4; ++p) {
      const int t = p * 16 + trow;
      const int tok = tok0 + t;
      float v[8];
      #pragma unroll
      for (int j = 0; j < 8; ++j) v[j] = sc[oct * 8 + j][t];
      f16x8 h, l;
      #pragma unroll
      for (int j = 0; j < 8; ++j) {
        const f16 hv = (f16)v[j];
        h[j] = hv;
        l[j] = (f16)((v[j] - (float)hv) * LO_SCALE);
      }
      // fragment-major: tile(32 tok), kslot(=oct), lane(=tok&31)
      const size_t off = (size_t)(tok >> 5) * 4096 + oct * 256 + (tok & 31) * 8;
      *(f16x8*)(xhi + off) = h;
      *(f16x8*)(xlo + off) = l;
    }
  } else {
    const int k0 = ((int)blockIdx.x - 1024) * 16;
    const int r = tid >> 4, dq16 = tid & 15;
    const int k = k0 + r;
    float ssum = 0.0f;
    #pragma unroll
    for (int hh = 0; hh < 2; ++hh) {
      const int dq = dq16 + 16 * hh;
      const float4 v = *(const float4*)(e + (size_t)k * ND + 4 * dq);
      ssum += v.x * v.x + v.y * v.y + v.z * v.z + v.w * v.w;
      float va[4] = {v.x, v.y, v.z, v.w};
      f16x4 hv, lv;
      #pragma unroll
      for (int j = 0; j < 4; ++j) {
        const f16 h = (f16)va[j];
        hv[j] = h;
        lv[j] = (f16)((va[j] - (float)h) * LO_SCALE);
      }
      const int sl = (dq >> 1) ^ (k & 15);            // 16B-slot swizzle
      const size_t off = (size_t)k * ND + sl * 8 + (dq & 1) * 4;
      *(f16x4*)(ehi + off) = hv;
      *(f16x4*)(elo + off) = lv;
    }
    #pragma unroll
    for (int m = 1; m < 16; m <<= 1) ssum += __shfl_xor(ssum, m, 64);
    if (dq16 == 0) ens[k] = 0.5f * ssum;
  }
}

// =============================================================== score ======
__global__ __launch_bounds__(256) void vq_score(const f16* __restrict__ xhi,
                                                const f16* __restrict__ xlo,
                                                const f16* __restrict__ ehi,
                                                const f16* __restrict__ elo,
                                                const float* __restrict__ ens,
                                                const float* __restrict__ e32,
                                                float* __restrict__ out) {
  __shared__ f16 eh_s[2][64 * 128];   // 2 x 16KB, [buf][code*128 + swz slot]
  __shared__ f16 el_s[2][64 * 128];   // 2 x 16KB
  __shared__ float ens_s[NK];         // 2KB

  const int tid = threadIdx.x;        // 0..255
  const int w = tid >> 6;             // wave 0..3
  const int lane = tid & 63;
  const int l31 = lane & 31;
  const int half = lane >> 5;
  const int T0 = (int)blockIdx.x * 128;
  const int tok = T0 + w * 32 + l31;  // this lane's token

  // --- prologue: stage chunk 0 + ens, load resident x B-frags ---
  __builtin_amdgcn_global_load_lds(ehi + tid * 8,        &eh_s[0][tid * 8],        16, 0, 0);
  __builtin_amdgcn_global_load_lds(ehi + 2048 + tid * 8, &eh_s[0][2048 + tid * 8], 16, 0, 0);
  __builtin_amdgcn_global_load_lds(ehi + 4096 + tid * 8, &eh_s[0][4096 + tid * 8], 16, 0, 0);
  __builtin_amdgcn_global_load_lds(ehi + 6144 + tid * 8, &eh_s[0][6144 + tid * 8], 16, 0, 0);
  __builtin_amdgcn_global_load_lds(elo + tid * 8,        &el_s[0][tid * 8],        16, 0, 0);
  __builtin_amdgcn_global_load_lds(elo + 2048 + tid * 8, &el_s[0][2048 + tid * 8], 16, 0, 0);
  __builtin_amdgcn_global_load_lds(elo + 4096 + tid * 8, &el_s[0][4096 + tid * 8], 16, 0, 0);
  __builtin_amdgcn_global_load_lds(elo + 6144 + tid * 8, &el_s[0][6144 + tid * 8], 16, 0, 0);

  // resident x fragments: frag(ks) at tile*4096 + (2ks+half)*256 + l31*8
  f16x8 Bh[8], Bl[8];
  {
    const size_t base = (size_t)(tok >> 5) * 4096 + (size_t)l31 * 8 + half * 256;
    #pragma unroll
    for (int ks = 0; ks < 8; ++ks) {
      Bh[ks] = *(const f16x8*)(xhi + base + ks * 512);
      Bl[ks] = *(const f16x8*)(xlo + base + ks * 512);
    }
  }
  ens_s[tid] = ens[tid];
  ens_s[tid + 256] = ens[tid + 256];
  __syncthreads();

  float bv = -3.0e38f;
  int bi = 0;
  int cur = 0;
  const int sbase = l31 & 15;         // swizzle key (== code&15 for row l31)

  for (int c = 0; c < 8; ++c) {
    if (c < 7) {  // stage next chunk into the other buffer (no VGPR staging)
      const f16* gh = ehi + (c + 1) * 8192;
      const f16* gl = elo + (c + 1) * 8192;
      f16* dh = &eh_s[cur ^ 1][0];
      f16* dl = &el_s[cur ^ 1][0];
      __builtin_amdgcn_global_load_lds(gh + tid * 8,        dh + tid * 8,        16, 0, 0);
      __builtin_amdgcn_global_load_lds(gh + 2048 + tid * 8, dh + 2048 + tid * 8, 16, 0, 0);
      __builtin_amdgcn_global_load_lds(gh + 4096 + tid * 8, dh + 4096 + tid * 8, 16, 0, 0);
      __builtin_amdgcn_global_load_lds(gh + 6144 + tid * 8, dh + 6144 + tid * 8, 16, 0, 0);
      __builtin_amdgcn_global_load_lds(gl + tid * 8,        dl + tid * 8,        16, 0, 0);
      __builtin_amdgcn_global_load_lds(gl + 2048 + tid * 8, dl + 2048 + tid * 8, 16, 0, 0);
      __builtin_amdgcn_global_load_lds(gl + 4096 + tid * 8, dl + 4096 + tid * 8, 16, 0, 0);
      __builtin_amdgcn_global_load_lds(gl + 6144 + tid * 8, dl + 6144 + tid * 8, 16, 0, 0);
    }

    #pragma unroll
    for (int cg = 0; cg < 2; ++cg) {
      const int r = cg * 32 + l31;            // lane's code row in chunk (A)
      const f16* ah = &eh_s[cur][r * 128];
      const f16* al = &el_s[cur][r * 128];
      f32x16 a1 = {}, a2 = {};
      #pragma unroll
      for (int ks = 0; ks < 8; ++ks) {
        const int sl = ((2 * ks + half) ^ sbase) * 8;
        const f16x8 Ah = *(const f16x8*)(ah + sl);
        const f16x8 Al = *(const f16x8*)(al + sl);
        a2 = __builtin_amdgcn_mfma_f32_32x32x16_f16(Al, Bh[ks], a2, 0, 0, 0);
        a1 = __builtin_amdgcn_mfma_f32_32x32x16_f16(Ah, Bh[ks], a1, 0, 0, 0);
        a2 = __builtin_amdgcn_mfma_f32_32x32x16_f16(Ah, Bl[ks], a2, 0, 0, 0);
      }
      // bias rows for this lane: rowr = (r&3) + 8*(r>>2) + 4*half, runs of 4
      const int kb = c * 64 + cg * 32 + 4 * half;
      const float4 b0 = *(const float4*)&ens_s[kb + 0];
      const float4 b1 = *(const float4*)&ens_s[kb + 8];
      const float4 b2 = *(const float4*)&ens_s[kb + 16];
      const float4 b3 = *(const float4*)&ens_s[kb + 24];
      const float bias[16] = {b0.x, b0.y, b0.z, b0.w, b1.x, b1.y, b1.z, b1.w,
                              b2.x, b2.y, b2.z, b2.w, b3.x, b3.y, b3.z, b3.w};
      #pragma unroll
      for (int rr = 0; rr < 16; ++rr) {
        const float s = a1[rr] + a2[rr] * LO_INV - bias[rr];
        const int code = kb + (rr & 3) + 8 * (rr >> 2);   // == c*64+cg*32+rowr
        if (s > bv) { bv = s; bi = code; }  // ascending code: > keeps lowest
      }
    }
    __syncthreads();   // next chunk staged; this buffer free for c+2
    cur ^= 1;
  }

  // merge across halves (same token for lane ^ 32)
  {
    const float ov = __shfl_xor(bv, 32, 64);
    const int oi = __shfl_xor(bi, 32, 64);
    if (ov > bv || (ov == bv && oi < bi)) { bv = ov; bi = oi; }
  }

  // fused output write: lane covers token `tok`, d-range half*64..+64
  {
    const int bb = tok >> 12;
    const int hw = tok & 4095;
    const float* er = e32 + (size_t)bi * ND + half * 64;
    float* ob = out + (size_t)bb * ND * NHW + (size_t)(half * 64) * NHW + hw;
    #pragma unroll
    for (int j4 = 0; j4 < 16; ++j4) {
      const float4 ev = *(const float4*)(er + j4 * 4);
      ob[(size_t)(j4 * 4 + 0) * NHW] = ev.x;
      ob[(size_t)(j4 * 4 + 1) * NHW] = ev.y;
      ob[(size_t)(j4 * 4 + 2) * NHW] = ev.z;
      ob[(size_t)(j4 * 4 + 3) * NHW] = ev.w;
    }
  }
}

// ======================================================== fp32 fallback =====
__global__ __launch_bounds__(128) void vq_enorm(const float* __restrict__ e,
                                                float* __restrict__ ensw) {
  const int k = blockIdx.x;
  const int d = threadIdx.x;
  const float v = e[k * ND + d];
  float s = v * v;
  #pragma unroll
  for (int off = 32; off > 0; off >>= 1) s += __shfl_down(s, off, 64);
  __shared__ float tmp[2];
  if ((d & 63) == 0) tmp[d >> 6] = s;
  __syncthreads();
  if (d == 0) ensw[k] = tmp[0] + tmp[1];
}

__global__ __launch_bounds__(256, 2) void vq_main_f32(const float* __restrict__ x,
                                                      const float* __restrict__ e,
                                                      const float* __restrict__ ensw,
                                                      float* __restrict__ out) {
  __shared__ float xs[ND][64];
  __shared__ float esh[ND][64];
  __shared__ float enh[NK];
  __shared__ float red_v[64][17];
  __shared__ int red_i[64][17];
  __shared__ int bidx[64];
  const int tid = threadIdx.x;
  const int b = blockIdx.x >> 6;
  const int hw0 = (blockIdx.x & 63) * 64;
  const float* xb = x + ((size_t)b * ND) * NHW;
  #pragma unroll
  for (int i = 0; i < 8; ++i) {
    const int f = tid + 256 * i;
    const int d = f >> 4, t4 = f & 15;
    const float4 v = *(const float4*)(xb + (size_t)d * NHW + hw0 + 4 * t4);
    *(float4*)&xs[d][4 * t4] = v;
  }
  #pragma unroll
  for (int i = 0; i < 2; ++i) enh[tid + 256 * i] = ensw[tid + 256 * i];
  const int t4 = tid & 15, m = tid >> 4;
  float bvv[4] = {-3.0e38f, -3.0e38f, -3.0e38f, -3.0e38f};
  int bii[4] = {0, 0, 0, 0};
  for (int kc = 0; kc < NK / 64; ++kc) {
    __syncthreads();
    #pragma unroll
    for (int i = 0; i < 8; ++i) {
      const int f = tid + 256 * i;
      const int kk = f & 63, dq = f >> 6;
      const float4 v = *(const float4*)(e + (size_t)(kc * 64 + kk) * ND + 4 * dq);
      esh[4 * dq + 0][kk] = v.x; esh[4 * dq + 1][kk] = v.y;
      esh[4 * dq + 2][kk] = v.z; esh[4 * dq + 3][kk] = v.w;
    }
    __syncthreads();
    float acc[4][4];
    #pragma unroll
    for (int a = 0; a < 4; ++a)
      #pragma unroll
      for (int cc = 0; cc < 4; ++cc) acc[a][cc] = 0.0f;
    #pragma unroll 8
    for (int d = 0; d < ND; ++d) {
      const float4 xv = *(const float4*)&xs[d][4 * t4];
      const float4 ev = *(const float4*)&esh[d][4 * m];
      const float xa[4] = {xv.x, xv.y, xv.z, xv.w};
      const float ea[4] = {ev.x, ev.y, ev.z, ev.w};
      #pragma unroll
      for (int a = 0; a < 4; ++a)
        #pragma unroll
        for (int cc = 0; cc < 4; ++cc) acc[a][cc] = fmaf(xa[a], ea[cc], acc[a][cc]);
    }
    const int kbase = kc * 64 + 4 * m;
    #pragma unroll
    for (int cc = 0; cc < 4; ++cc) {
      const float bias = 0.5f * enh[kbase + cc];
      const int kg = kbase + cc;
      #pragma unroll
      for (int a = 0; a < 4; ++a) {
        const float s = acc[a][cc] - bias;
        if (s > bvv[a] || (s == bvv[a] && kg < bii[a])) { bvv[a] = s; bii[a] = kg; }
      }
    }
  }
  #pragma unroll
  for (int a = 0; a < 4; ++a) { red_v[4 * t4 + a][m] = bvv[a]; red_i[4 * t4 + a][m] = bii[a]; }
  __syncthreads();
  if (tid < 64) {
    float v = red_v[tid][0]; int ix = red_i[tid][0];
    #pragma unroll
    for (int j = 1; j < 16; ++j) {
      const float vj = red_v[tid][j]; const int ij = red_i[tid][j];
      if (vj > v || (vj == v && ij < ix)) { v = vj; ix = ij; }
    }
    bidx[tid] = ix;
  }
  __syncthreads();
  const int t = tid & 63, dgg = tid >> 6;
  const float* er = e + (size_t)bidx[t] * ND;
  float* ob = out + ((size_t)b * ND) * NHW + hw0 + t;
  #pragma unroll
  for (int i = 0; i < 32; ++i) ob[(size_t)(dgg * 32 + i) * NHW] = er[dgg * 32 + i];
}

// --------------------------------------------------------------- launch -----
extern "C" void kernel_launch(void* const* d_in, const int* in_sizes, int n_in,
                              void* d_out, int out_size, void* d_ws, size_t ws_size,
                              hipStream_t stream) {
  const float* x = (const float*)d_in[0];
  const float* e = (const float*)d_in[1];
  float* out = (float*)d_out;
  char* ws = (char*)d_ws;

  if (ws_size >= WS_NEED) {
    f16* xhi = (f16*)(ws + WS_XHI);
    f16* xlo = (f16*)(ws + WS_XLO);
    f16* ehi = (f16*)(ws + WS_EHI);
    f16* elo = (f16*)(ws + WS_ELO);
    float* ens = (float*)(ws + WS_ENS);
    vq_prep<<<1056, 256, 0, stream>>>(x, e, xhi, xlo, ehi, elo, ens);
    vq_score<<<512, 256, 0, stream>>>(xhi, xlo, ehi, elo, ens, e, out);
  } else {
    float* ensw = (float*)d_ws;
    vq_enorm<<<NK, 128, 0, stream>>>(e, ensw);
    vq_main_f32<<<16 * 64, 256, 0, stream>>>(x, e, ensw, out);
  }
}

// Round 10
// 45.453 us; speedup vs baseline: 1.8361x; 1.1553x over previous
//
#include <hip/hip_runtime.h>

// VQ-VAE vector quantizer, MI355X — v8: fully-fused score (x read direct from
// NCHW + in-register fp16 split), e-only prep, single-buffer 64-code LDS chunks.
// score(t,k) = x_t . e_k - 0.5*||e_k||^2  (argmax == argmin distance)
// x.e = xh.eh + (xh.el' + xl'.eh)/2048, *_lo' = (v - fp16(v))*2048 as fp16.

typedef _Float16 f16;
typedef _Float16 f16x4 __attribute__((ext_vector_type(4)));
typedef _Float16 f16x8 __attribute__((ext_vector_type(8)));
typedef float f32x16 __attribute__((ext_vector_type(16)));

#define ND 128
#define NK 512
#define NHW 4096
#define LO_SCALE 2048.0f
#define LO_INV (1.0f / 2048.0f)

// workspace layout (bytes): e-split only
#define WS_EHI 0
#define WS_ELO 131072u
#define WS_ENS 262144u
#define WS_NEED 264192u

// ================================================================ prep ======
// 32 blocks x 256 thr: split e SWIZZLED (16B slot ^= code&15) + 0.5*||e||^2
__global__ __launch_bounds__(256) void vq_prep_e(const float* __restrict__ e,
                                                 f16* __restrict__ ehi, f16* __restrict__ elo,
                                                 float* __restrict__ ens) {
  const int tid = threadIdx.x;
  const int k0 = (int)blockIdx.x * 16;
  const int r = tid >> 4, dq16 = tid & 15;
  const int k = k0 + r;
  float ssum = 0.0f;
  #pragma unroll
  for (int hh = 0; hh < 2; ++hh) {
    const int dq = dq16 + 16 * hh;
    const float4 v = *(const float4*)(e + (size_t)k * ND + 4 * dq);
    ssum += v.x * v.x + v.y * v.y + v.z * v.z + v.w * v.w;
    float va[4] = {v.x, v.y, v.z, v.w};
    f16x4 hv, lv;
    #pragma unroll
    for (int j = 0; j < 4; ++j) {
      const f16 h = (f16)va[j];
      hv[j] = h;
      lv[j] = (f16)((va[j] - (float)h) * LO_SCALE);
    }
    const int sl = (dq >> 1) ^ (k & 15);            // 16B-slot swizzle
    const size_t off = (size_t)k * ND + sl * 8 + (dq & 1) * 4;
    *(f16x4*)(ehi + off) = hv;
    *(f16x4*)(elo + off) = lv;
  }
  #pragma unroll
  for (int m = 1; m < 16; m <<= 1) ssum += __shfl_xor(ssum, m, 64);
  if (dq16 == 0) ens[k] = 0.5f * ssum;
}

// =============================================================== score ======
// grid 512 x 256 thr (4 waves). Block = 128 tokens; wave owns 32 (B in regs).
// e streams through ONE 32KB LDS buffer, 8 chunks x 64 codes, global_load_lds.
__global__ __launch_bounds__(256) void vq_score(const float* __restrict__ x,
                                                const f16* __restrict__ ehi,
                                                const f16* __restrict__ elo,
                                                const float* __restrict__ ens,
                                                const float* __restrict__ e32,
                                                float* __restrict__ out) {
  __shared__ f16 eh_s[64 * 128];      // 16KB [code*128 + swz slot]
  __shared__ f16 el_s[64 * 128];      // 16KB
  __shared__ float ens_s[NK];         // 2KB

  const int tid = threadIdx.x;        // 0..255
  const int w = tid >> 6;             // wave 0..3
  const int lane = tid & 63;
  const int l31 = lane & 31;
  const int half = lane >> 5;
  const int T0 = (int)blockIdx.x * 128;
  const int tok = T0 + w * 32 + l31;  // this lane's token
  const int bb = tok >> 12;
  const int hw = tok & 4095;

  // stage chunk 0 (zero staging VGPRs)
  #pragma unroll
  for (int p = 0; p < 4; ++p) {
    __builtin_amdgcn_global_load_lds(ehi + p * 2048 + tid * 8, &eh_s[p * 2048 + tid * 8], 16, 0, 0);
    __builtin_amdgcn_global_load_lds(elo + p * 2048 + tid * 8, &el_s[p * 2048 + tid * 8], 16, 0, 0);
  }

  // x: direct strided-coalesced loads from NCHW + in-register fp16 split,
  // already in fragment order (d-octet = 2ks+half)
  f16x8 Bh[8], Bl[8];
  {
    const float* xb = x + (size_t)bb * ND * NHW + hw;
    #pragma unroll
    for (int ks = 0; ks < 8; ++ks) {
      const int oct = 2 * ks + half;
      #pragma unroll
      for (int j = 0; j < 8; ++j) {
        const float v = xb[(size_t)(oct * 8 + j) * NHW];
        const f16 hv = (f16)v;
        Bh[ks][j] = hv;
        Bl[ks][j] = (f16)((v - (float)hv) * LO_SCALE);
      }
    }
  }
  ens_s[tid] = ens[tid];
  ens_s[tid + 256] = ens[tid + 256];
  __syncthreads();   // drains chunk-0 stage (vmcnt 0) + x loads

  float bv = -3.0e38f;
  int bi = 0;
  const int sbase = l31 & 15;         // swizzle key (== code&15 for row l31)

  for (int c = 0; c < 8; ++c) {
    #pragma unroll
    for (int cg = 0; cg < 2; ++cg) {
      const int r = cg * 32 + l31;              // lane's code row in chunk (A)
      const f16* ah = &eh_s[r * 128];
      const f16* al = &el_s[r * 128];
      f32x16 a1 = {}, a2 = {};
      __builtin_amdgcn_s_setprio(1);
      #pragma unroll
      for (int ks = 0; ks < 8; ++ks) {
        const int sl = ((2 * ks + half) ^ sbase) * 8;
        const f16x8 Ah = *(const f16x8*)(ah + sl);
        const f16x8 Al = *(const f16x8*)(al + sl);
        a2 = __builtin_amdgcn_mfma_f32_32x32x16_f16(Al, Bh[ks], a2, 0, 0, 0);
        a1 = __builtin_amdgcn_mfma_f32_32x32x16_f16(Ah, Bh[ks], a1, 0, 0, 0);
        a2 = __builtin_amdgcn_mfma_f32_32x32x16_f16(Ah, Bl[ks], a2, 0, 0, 0);
      }
      __builtin_amdgcn_s_setprio(0);
      // bias rows for this lane: rowr = (rr&3) + 8*(rr>>2) + 4*half
      const int kb = c * 64 + cg * 32 + 4 * half;
      const float4 b0 = *(const float4*)&ens_s[kb + 0];
      const float4 b1 = *(const float4*)&ens_s[kb + 8];
      const float4 b2 = *(const float4*)&ens_s[kb + 16];
      const float4 b3 = *(const float4*)&ens_s[kb + 24];
      const float bias[16] = {b0.x, b0.y, b0.z, b0.w, b1.x, b1.y, b1.z, b1.w,
                              b2.x, b2.y, b2.z, b2.w, b3.x, b3.y, b3.z, b3.w};
      #pragma unroll
      for (int rr = 0; rr < 16; ++rr) {
        const float s = a1[rr] + a2[rr] * LO_INV - bias[rr];
        const int code = kb + (rr & 3) + 8 * (rr >> 2);
        if (s > bv) { bv = s; bi = code; }  // ascending code: > keeps lowest
      }
    }
    __syncthreads();                        // everyone done reading buffer
    if (c < 7) {                            // stage next chunk, same buffer
      const f16* gh = ehi + (c + 1) * 8192;
      const f16* gl = elo + (c + 1) * 8192;
      #pragma unroll
      for (int p = 0; p < 4; ++p) {
        __builtin_amdgcn_global_load_lds(gh + p * 2048 + tid * 8, &eh_s[p * 2048 + tid * 8], 16, 0, 0);
        __builtin_amdgcn_global_load_lds(gl + p * 2048 + tid * 8, &el_s[p * 2048 + tid * 8], 16, 0, 0);
      }
      __syncthreads();                      // staged + drained
    }
  }

  // merge across halves (same token for lane ^ 32)
  {
    const float ov = __shfl_xor(bv, 32, 64);
    const int oi = __shfl_xor(bi, 32, 64);
    if (ov > bv || (ov == bv && oi < bi)) { bv = ov; bi = oi; }
  }

  // fused output write: lane covers token `tok`, d-range half*64..+64
  {
    const float* er = e32 + (size_t)bi * ND + half * 64;
    float* ob = out + (size_t)bb * ND * NHW + (size_t)(half * 64) * NHW + hw;
    #pragma unroll
    for (int j4 = 0; j4 < 16; ++j4) {
      const float4 ev = *(const float4*)(er + j4 * 4);
      ob[(size_t)(j4 * 4 + 0) * NHW] = ev.x;
      ob[(size_t)(j4 * 4 + 1) * NHW] = ev.y;
      ob[(size_t)(j4 * 4 + 2) * NHW] = ev.z;
      ob[(size_t)(j4 * 4 + 3) * NHW] = ev.w;
    }
  }
}

// ======================================================== fp32 fallback =====
__global__ __launch_bounds__(128) void vq_enorm(const float* __restrict__ e,
                                                float* __restrict__ ensw) {
  const int k = blockIdx.x;
  const int d = threadIdx.x;
  const float v = e[k * ND + d];
  float s = v * v;
  #pragma unroll
  for (int off = 32; off > 0; off >>= 1) s += __shfl_down(s, off, 64);
  __shared__ float tmp[2];
  if ((d & 63) == 0) tmp[d >> 6] = s;
  __syncthreads();
  if (d == 0) ensw[k] = tmp[0] + tmp[1];
}

__global__ __launch_bounds__(256, 2) void vq_main_f32(const float* __restrict__ x,
                                                      const float* __restrict__ e,
                                                      const float* __restrict__ ensw,
                                                      float* __restrict__ out) {
  __shared__ float xs[ND][64];
  __shared__ float esh[ND][64];
  __shared__ float enh[NK];
  __shared__ float red_v[64][17];
  __shared__ int red_i[64][17];
  __shared__ int bidx[64];
  const int tid = threadIdx.x;
  const int b = blockIdx.x >> 6;
  const int hw0 = (blockIdx.x & 63) * 64;
  const float* xb = x + ((size_t)b * ND) * NHW;
  #pragma unroll
  for (int i = 0; i < 8; ++i) {
    const int f = tid + 256 * i;
    const int d = f >> 4, t4 = f & 15;
    const float4 v = *(const float4*)(xb + (size_t)d * NHW + hw0 + 4 * t4);
    *(float4*)&xs[d][4 * t4] = v;
  }
  #pragma unroll
  for (int i = 0; i < 2; ++i) enh[tid + 256 * i] = ensw[tid + 256 * i];
  const int t4 = tid & 15, m = tid >> 4;
  float bvv[4] = {-3.0e38f, -3.0e38f, -3.0e38f, -3.0e38f};
  int bii[4] = {0, 0, 0, 0};
  for (int kc = 0; kc < NK / 64; ++kc) {
    __syncthreads();
    #pragma unroll
    for (int i = 0; i < 8; ++i) {
      const int f = tid + 256 * i;
      const int kk = f & 63, dq = f >> 6;
      const float4 v = *(const float4*)(e + (size_t)(kc * 64 + kk) * ND + 4 * dq);
      esh[4 * dq + 0][kk] = v.x; esh[4 * dq + 1][kk] = v.y;
      esh[4 * dq + 2][kk] = v.z; esh[4 * dq + 3][kk] = v.w;
    }
    __syncthreads();
    float acc[4][4];
    #pragma unroll
    for (int a = 0; a < 4; ++a)
      #pragma unroll
      for (int cc = 0; cc < 4; ++cc) acc[a][cc] = 0.0f;
    #pragma unroll 8
    for (int d = 0; d < ND; ++d) {
      const float4 xv = *(const float4*)&xs[d][4 * t4];
      const float4 ev = *(const float4*)&esh[d][4 * m];
      const float xa[4] = {xv.x, xv.y, xv.z, xv.w};
      const float ea[4] = {ev.x, ev.y, ev.z, ev.w};
      #pragma unroll
      for (int a = 0; a < 4; ++a)
        #pragma unroll
        for (int cc = 0; cc < 4; ++cc) acc[a][cc] = fmaf(xa[a], ea[cc], acc[a][cc]);
    }
    const int kbase = kc * 64 + 4 * m;
    #pragma unroll
    for (int cc = 0; cc < 4; ++cc) {
      const float bias = 0.5f * enh[kbase + cc];
      const int kg = kbase + cc;
      #pragma unroll
      for (int a = 0; a < 4; ++a) {
        const float s = acc[a][cc] - bias;
        if (s > bvv[a] || (s == bvv[a] && kg < bii[a])) { bvv[a] = s; bii[a] = kg; }
      }
    }
  }
  #pragma unroll
  for (int a = 0; a < 4; ++a) { red_v[4 * t4 + a][m] = bvv[a]; red_i[4 * t4 + a][m] = bii[a]; }
  __syncthreads();
  if (tid < 64) {
    float v = red_v[tid][0]; int ix = red_i[tid][0];
    #pragma unroll
    for (int j = 1; j < 16; ++j) {
      const float vj = red_v[tid][j]; const int ij = red_i[tid][j];
      if (vj > v || (vj == v && ij < ix)) { v = vj; ix = ij; }
    }
    bidx[tid] = ix;
  }
  __syncthreads();
  const int t = tid & 63, dgg = tid >> 6;
  const float* er = e + (size_t)bidx[t] * ND;
  float* ob = out + ((size_t)b * ND) * NHW + hw0 + t;
  #pragma unroll
  for (int i = 0; i < 32; ++i) ob[(size_t)(dgg * 32 + i) * NHW] = er[dgg * 32 + i];
}

// --------------------------------------------------------------- launch -----
extern "C" void kernel_launch(void* const* d_in, const int* in_sizes, int n_in,
                              void* d_out, int out_size, void* d_ws, size_t ws_size,
                              hipStream_t stream) {
  const float* x = (const float*)d_in[0];
  const float* e = (const float*)d_in[1];
  float* out = (float*)d_out;
  char* ws = (char*)d_ws;

  if (ws_size >= WS_NEED) {
    f16* ehi = (f16*)(ws + WS_EHI);
    f16* elo = (f16*)(ws + WS_ELO);
    float* ens = (float*)(ws + WS_ENS);
    vq_prep_e<<<32, 256, 0, stream>>>(e, ehi, elo, ens);
    vq_score<<<512, 256, 0, stream>>>(x, ehi, elo, ens, e, out);
  } else {
    float* ensw = (float*)d_ws;
    vq_enorm<<<NK, 128, 0, stream>>>(e, ensw);
    vq_main_f32<<<16 * 64, 256, 0, stream>>>(x, e, ensw, out);
  }
}